// Round 4
// baseline (744.949 us; speedup 1.0000x reference)
//
#include <hip/hip_runtime.h>

typedef __attribute__((ext_vector_type(8))) short bf16x8;
typedef __attribute__((ext_vector_type(8))) unsigned short u16x8;
typedef __attribute__((ext_vector_type(4))) unsigned short u16x4;
typedef __attribute__((ext_vector_type(4))) float f32x4;

#define DEV static __device__ __forceinline__

DEV unsigned short f2bf(float f){
  unsigned u = __float_as_uint(f);
  u += 0x7fff + ((u>>16)&1);
  return (unsigned short)(u>>16);
}
DEV float bf2f(unsigned short b){ return __uint_as_float(((unsigned)b)<<16); }

DEV void gll16(const void* g, void* l){
  __builtin_amdgcn_global_load_lds((__attribute__((address_space(1))) unsigned*)(void*)g,
                                   (__attribute__((address_space(3))) unsigned*)l, 16, 0, 0);
}

// ---------------- cast fp32 -> bf16 (vectorized) ----------------
__global__ void k_cast(const float* __restrict__ x, unsigned short* __restrict__ y, int n4){
  int i = blockIdx.x*256 + threadIdx.x;
  if (i >= n4) return;
  f32x4 v = ((const f32x4*)x)[i];
  u16x4 o = { f2bf(v.x), f2bf(v.y), f2bf(v.z), f2bf(v.w) };
  ((u16x4*)y)[i] = o;
}

// ---------------- 6-segment weight cast (one launch for all QKV weights) ----------------
__global__ void k_castW(const float* __restrict__ s0, const float* __restrict__ s1,
                        const float* __restrict__ s2, const float* __restrict__ s3,
                        const float* __restrict__ s4, const float* __restrict__ s5,
                        unsigned short* __restrict__ y){
  unsigned i = blockIdx.x*256 + threadIdx.x;          // < 6*2359296
  unsigned seg = i / 2359296u;                        // uniform per block (9216 blocks/seg)
  unsigned off = i - seg*2359296u;
  const float* s = seg==0?s0: seg==1?s1: seg==2?s2: seg==3?s3: seg==4?s4: s5;
  f32x4 v = ((const f32x4*)s)[off];
  u16x4 o = { f2bf(v.x), f2bf(v.y), f2bf(v.z), f2bf(v.w) };
  ((u16x4*)y)[i] = o;
}

// ---------------- merged QKV GEMM: Y[3072][9216] = X @ [Wq|Wk|Wv]^T (+bias) ----------------
// Row-block-diagonal over weights: rows >= rows_img use the enc weight triple.
__global__ __launch_bounds__(256) void k_gemmQKV(
    const unsigned short* __restrict__ X,
    const unsigned short* __restrict__ Wimg, const unsigned short* __restrict__ Wenc,
    unsigned short* __restrict__ Y,
    const float* __restrict__ b0, const float* __restrict__ b1, const float* __restrict__ b2,
    const float* __restrict__ b3, const float* __restrict__ b4, const float* __restrict__ b5,
    int rows_img)
{
  const int K = 3072, N = 9216;
  __shared__ unsigned short As[2][4096];
  __shared__ unsigned short Bs[2][4096];
  const int t = threadIdx.x, w = t>>6, l = t&63;
  const int by = blockIdx.y;
  const int sec = by>=48 ? 2 : (by>=24 ? 1 : 0);      // Q/K/V section
  const int Cl = (by - sec*24)*128;                   // col base within 3072 section
  const int R = blockIdx.x*128;
  const bool enc = (R >= rows_img);
  const unsigned short* Wp = (enc ? Wenc : Wimg) + (long)sec*9437184 + (long)Cl*K;
  const float* bias = enc ? (sec==0?b3: sec==1?b4: b5) : (sec==0?b0: sec==1?b1: b2);
  const int wr = w>>1, wc = w&1;
  f32x4 acc[4][4] = {};

  auto stage = [&](int buf, int kt){
    const int k0 = kt*32;
    #pragma unroll
    for (int c=0;c<2;c++){
      int row = c*64 + (t>>2);
      int scol = ((t&3)<<3) ^ ((row&3)<<3);           // 4-way XOR pre-swizzle of source
      gll16(X + (long)(R+row)*K + k0 + scol, &As[buf][c*2048 + w*512]);
      gll16(Wp + (long)row*K + k0 + scol, &Bs[buf][c*2048 + w*512]);
    }
  };

  stage(0,0);
  int buf = 0;
  for (int kt=0; kt<96; kt++){
    __syncthreads();
    if (kt+1 < 96) stage(buf^1, kt+1);
    bf16x8 a[4], b[4];
    #pragma unroll
    for (int m=0;m<4;m++){
      int ar = wr*64 + m*16 + (l&15);
      int ac = ((l>>4)<<3) ^ ((ar&3)<<3);
      a[m] = *(const bf16x8*)&As[buf][ar*32 + ac];
      int br = wc*64 + m*16 + (l&15);
      int bc2 = ((l>>4)<<3) ^ ((br&3)<<3);
      b[m] = *(const bf16x8*)&Bs[buf][br*32 + bc2];
    }
    #pragma unroll
    for (int m=0;m<4;m++)
      #pragma unroll
      for (int n=0;n<4;n++)
        acc[m][n] = __builtin_amdgcn_mfma_f32_16x16x32_bf16(a[m], b[n], acc[m][n], 0,0,0);
    buf ^= 1;
  }

  #pragma unroll
  for (int m=0;m<4;m++){
    int row = R + wr*64 + m*16 + ((l>>4)<<2);
    #pragma unroll
    for (int n=0;n<4;n++){
      int cl = wc*64 + n*16 + (l&15);
      float bvv = bias[Cl + cl];
      long col = (long)by*128 + cl;
      #pragma unroll
      for (int r=0;r<4;r++)
        Y[(long)(row+r)*N + col] = f2bf(acc[m][n][r] + bvv);
    }
  }
}

// ---------------- fused output GEMM (block-diagonal over rows) ----------------
__global__ __launch_bounds__(256) void k_gemmO(
    const unsigned short* __restrict__ X, const unsigned short* __restrict__ Wf,
    float* __restrict__ out, const float* __restrict__ bo, const float* __restrict__ bao)
{
  const int K = 3072;
  __shared__ unsigned short As[2][4096];
  __shared__ unsigned short Bs[2][4096];
  const int t = threadIdx.x, w = t>>6, l = t&63;
  const int bx = blockIdx.x, by = blockIdx.y;
  const bool enc = bx >= 16;
  const unsigned short* Wp = Wf + (enc ? 9437184 : 0);
  const float* bias = enc ? bao : bo;
  const int R = bx*128, C = by*128;
  long xbase, obase;
  if (!enc){ xbase = (long)(R>>10)*1536 + 512 + (R&1023); obase = (long)R*3072; }
  else { int Rp = R-2048; xbase = (long)(Rp>>9)*1536 + (Rp&511); obase = 6291456 + (long)Rp*3072; }
  const int wr = w>>1, wc = w&1;
  f32x4 acc[4][4] = {};

  auto stage = [&](int buf, int kt){
    const int k0 = kt*32;
    #pragma unroll
    for (int c=0;c<2;c++){
      int row = c*64 + (t>>2);
      int scol = ((t&3)<<3) ^ ((row&3)<<3);
      gll16(X + (xbase+row)*K + k0 + scol, &As[buf][c*2048 + w*512]);
      gll16(Wp + (long)(C+row)*K + k0 + scol, &Bs[buf][c*2048 + w*512]);
    }
  };

  stage(0,0);
  int buf = 0;
  for (int kt=0; kt<96; kt++){
    __syncthreads();
    if (kt+1 < 96) stage(buf^1, kt+1);
    bf16x8 a[4], b[4];
    #pragma unroll
    for (int m=0;m<4;m++){
      int ar = wr*64 + m*16 + (l&15);
      int ac = ((l>>4)<<3) ^ ((ar&3)<<3);
      a[m] = *(const bf16x8*)&As[buf][ar*32 + ac];
      int br = wc*64 + m*16 + (l&15);
      int bc2 = ((l>>4)<<3) ^ ((br&3)<<3);
      b[m] = *(const bf16x8*)&Bs[buf][br*32 + bc2];
    }
    #pragma unroll
    for (int m=0;m<4;m++)
      #pragma unroll
      for (int n=0;n<4;n++)
        acc[m][n] = __builtin_amdgcn_mfma_f32_16x16x32_bf16(a[m], b[n], acc[m][n], 0,0,0);
    buf ^= 1;
  }

  #pragma unroll
  for (int m=0;m<4;m++){
    int rl = wr*64 + m*16 + ((l>>4)<<2);
    #pragma unroll
    for (int n=0;n<4;n++){
      int col = C + wc*64 + n*16 + (l&15);
      float bvv = bias[col];
      #pragma unroll
      for (int r=0;r<4;r++)
        out[obase + (long)(rl+r)*3072 + col] = acc[m][n][r] + bvv;
    }
  }
}

// ---------------- fused RMSNorm + RoPE postprocess (one wave per (token,head)) ----------------
__global__ void k_ppqk(const unsigned short* __restrict__ Y, int ystr, int yoff,
    const float* __restrict__ nw,
    const float* __restrict__ cs, const float* __restrict__ sn, unsigned short* __restrict__ dst,
    int T_log2, int tpb_log2, int dest_off, int S, int no_batch,
    int pos_off, int pos_mask, float qscale)
{
  int rid = blockIdx.x*4 + (threadIdx.x>>6);
  int l = threadIdx.x & 63;
  int h = rid >> T_log2, tk = rid & ((1<<T_log2)-1);
  unsigned pair = *(const unsigned*)(Y + (long)tk*ystr + yoff + h*128 + 2*l);
  float x0 = bf2f((unsigned short)(pair&0xffff));
  float x1 = bf2f((unsigned short)(pair>>16));
  float ss = x0*x0 + x1*x1;
  #pragma unroll
  for (int m=1;m<64;m<<=1) ss += __shfl_xor(ss, m);
  float rr = rsqrtf(ss*(1.0f/128.0f) + 1e-6f);
  x0 *= rr*nw[2*l]; x1 *= rr*nw[2*l+1];
  int p = pos_off + (tk & pos_mask);
  float c0 = cs[p*128 + 2*l], c1 = cs[p*128 + 2*l+1];
  float s0 = sn[p*128 + 2*l], s1 = sn[p*128 + 2*l+1];
  float o0 = (x0*c0 - x1*s0)*qscale;
  float o1 = (x1*c1 + x0*s1)*qscale;
  long idx;
  if (no_batch) idx = (long)h*S + tk;
  else {
    int b = tk >> tpb_log2;
    int sq = dest_off + (tk & ((1<<tpb_log2)-1));
    idx = (long)(b*24+h)*S + sq;
  }
  unsigned out = (unsigned)f2bf(o0) | ((unsigned)f2bf(o1)<<16);
  *(unsigned*)(dst + idx*128 + 2*l) = out;
}

// ---------------- V reorder + transpose: Vt[(b,)h][d][j] ----------------
__global__ void k_ppv(const unsigned short* __restrict__ Y, int ystr, int yoff,
                      unsigned short* __restrict__ Vt, int vstr, int no_batch)
{
  __shared__ unsigned short tileS[64][136];
  int t = threadIdx.x, h = blockIdx.y;
  int tile0 = blockIdx.x*64;
  #pragma unroll
  for (int c=0;c<4;c++){
    int j = c*16 + (t>>4), col = (t&15)*8;
    *(u16x8*)&tileS[j][col] = *(const u16x8*)(Y + (long)(tile0+j)*ystr + yoff + h*128 + col);
  }
  __syncthreads();
  int d = t>>1, half = t&1;
  unsigned short tmp[32];
  #pragma unroll
  for (int i=0;i<32;i++) tmp[i] = tileS[half*32+i][d];
  long base;
  if (no_batch) base = ((long)h*128 + d)*vstr + tile0 + half*32;
  else { int b = tile0>>9; base = ((long)(b*24+h)*128 + d)*vstr + (tile0&511) + half*32; }
  #pragma unroll
  for (int k=0;k<4;k++) *(u16x8*)(Vt + base + k*8) = *(const u16x8*)&tmp[k*8];
}

// ---------------- flash attention: 64 Q-rows/block, KV tiles of 64 ----------------
// K double-buffered (prefetch jt+1 at tile top); V staged at tile top, consumed after
// mid-tile barrier (overlaps QK+softmax). Defer-max THR=8 (log2 domain), per-lane
// partial sums reduced once at end.
__global__ __launch_bounds__(256) void k_attn(
    const unsigned short* __restrict__ Q,
    const unsigned short* __restrict__ Ke, const unsigned short* __restrict__ Ki,
    const unsigned short* __restrict__ Ve, const unsigned short* __restrict__ Vi,
    unsigned short* __restrict__ AO)
{
  __shared__ unsigned short Ks[2][8192];       // [64 kv][128 d], XOR-swizzled, dbuf
  __shared__ unsigned short Vs[8192];          // [128 d][64 kv], XOR-swizzled
  __shared__ unsigned short Ps[4][1408];       // per-wave P tile [16][88]
  const int t = threadIdx.x, w = t>>6, l = t&63;
  const int h = blockIdx.y, b = blockIdx.z;
  const int bh = b*24 + h;
  const int q0 = blockIdx.x*64 + w*16;

  auto stageK = [&](int bufi, int jt){
    const unsigned short* ksrc = (jt < 8) ? Ke + ((long)bh*512 + jt*64)*128
                                          : Ki + ((long)h*2048 + (jt-8)*64)*128;
    #pragma unroll
    for (int c=0;c<4;c++){
      int row = c*16 + (t>>4);
      int col = ((t&15)<<3) ^ ((row&7)<<3);
      gll16(ksrc + row*128 + col, &Ks[bufi][c*2048 + w*512]);
    }
  };
  auto stageV = [&](int jt){
    const unsigned short* vsrc; long vstr;
    if (jt < 8){ vsrc = Ve + (long)bh*65536 + jt*64; vstr = 512; }
    else { vsrc = Vi + (long)h*262144 + (jt-8)*64; vstr = 2048; }
    #pragma unroll
    for (int c=0;c<4;c++){
      int row = c*32 + (t>>3);
      int col = ((t&7)<<3) ^ ((row&7)<<3);
      gll16(vsrc + (long)row*vstr + col, &Vs[c*2048 + w*512]);
    }
  };

  bf16x8 qf[4];
  {
    const unsigned short* qp = Q + ((long)bh*1536 + q0 + (l&15))*128 + ((l>>4)<<3);
    #pragma unroll
    for (int kc=0;kc<4;kc++) qf[kc] = *(const bf16x8*)(qp + kc*32);
  }
  f32x4 o[8] = {};
  float mx[4] = {-1e30f,-1e30f,-1e30f,-1e30f};
  float ls[4] = {0,0,0,0};

  stageK(0, 0);
  for (int jt=0; jt<40; jt++){
    __syncthreads();                 // K(jt) ready; Vs free (read in jt-1 complete)
    stageV(jt);                      // overlaps QK + softmax below
    if (jt+1 < 40) stageK((jt+1)&1, jt+1);

    const unsigned short* Kb = Ks[jt&1];
    f32x4 sf[4];
    __builtin_amdgcn_s_setprio(1);
    #pragma unroll
    for (int ct=0;ct<4;ct++){
      f32x4 s = {};
      #pragma unroll
      for (int kc=0;kc<4;kc++){
        int krow = ct*16 + (l&15);
        int kcol = (kc*32 + ((l>>4)<<3)) ^ ((krow&7)<<3);
        bf16x8 kb = *(const bf16x8*)&Kb[krow*128 + kcol];
        s = __builtin_amdgcn_mfma_f32_16x16x32_bf16(qf[kc], kb, s, 0,0,0);
      }
      sf[ct] = s;
    }
    __builtin_amdgcn_s_setprio(0);

    float pm[4]; int ok = 1;
    #pragma unroll
    for (int r=0;r<4;r++){
      pm[r] = fmaxf(fmaxf(sf[0][r],sf[1][r]), fmaxf(sf[2][r],sf[3][r]));
      ok &= (pm[r] <= mx[r] + 8.0f);
    }
    if (!__all(ok)){
      #pragma unroll
      for (int r=0;r<4;r++){
        float tmax = pm[r];
        #pragma unroll
        for (int m=1;m<16;m<<=1) tmax = fmaxf(tmax, __shfl_xor(tmax, m));
        float mn = fmaxf(mx[r], tmax);
        float al = exp2f(mx[r]-mn);
        mx[r] = mn;
        ls[r] *= al;
        #pragma unroll
        for (int f=0;f<8;f++) o[f][r] *= al;
      }
    }
    #pragma unroll
    for (int ct=0;ct<4;ct++){
      #pragma unroll
      for (int r=0;r<4;r++){
        float pv = exp2f(sf[ct][r]-mx[r]);
        ls[r] += pv;
        int prow = ((l>>4)<<2) + r;
        Ps[w][prow*88 + ct*16 + (l&15)] = f2bf(pv);
      }
    }
    __syncthreads();                 // V(jt) landed (drains vmcnt); K(jt+1) likely landed too

    bf16x8 pa[2];
    #pragma unroll
    for (int kc=0;kc<2;kc++)
      pa[kc] = *(const bf16x8*)&Ps[w][(l&15)*88 + kc*32 + ((l>>4)<<3)];
    __builtin_amdgcn_s_setprio(1);
    #pragma unroll
    for (int f=0;f<8;f++){
      #pragma unroll
      for (int kc=0;kc<2;kc++){
        int vrow = f*16 + (l&15);
        int vcol = (kc*32 + ((l>>4)<<3)) ^ ((vrow&7)<<3);
        bf16x8 vb = *(const bf16x8*)&Vs[vrow*64 + vcol];
        o[f] = __builtin_amdgcn_mfma_f32_16x16x32_bf16(pa[kc], vb, o[f], 0,0,0);
      }
    }
    __builtin_amdgcn_s_setprio(0);
  }

  #pragma unroll
  for (int r=0;r<4;r++){
    #pragma unroll
    for (int m=1;m<16;m<<=1) ls[r] += __shfl_xor(ls[r], m);
  }
  #pragma unroll
  for (int r=0;r<4;r++){
    int qrow = q0 + ((l>>4)<<2) + r;
    float inv = 1.0f/ls[r];
    #pragma unroll
    for (int f=0;f<8;f++){
      AO[((long)b*1536 + qrow)*3072 + h*128 + f*16 + (l&15)] = f2bf(o[f][r]*inv);
    }
  }
}

// ---------------- host launch ----------------
extern "C" void kernel_launch(void* const* d_in, const int* in_sizes, int n_in,
                              void* d_out, int out_size, void* d_ws, size_t ws_size,
                              hipStream_t stream)
{
  const float* hs  = (const float*)d_in[0];
  const float* ehs = (const float*)d_in[1];
  const float* rc  = (const float*)d_in[2];
  const float* rs_ = (const float*)d_in[3];
  const float* wq = (const float*)d_in[4];  const float* bq = (const float*)d_in[5];
  const float* wk = (const float*)d_in[6];  const float* bk = (const float*)d_in[7];
  const float* wv = (const float*)d_in[8];  const float* bv = (const float*)d_in[9];
  const float* waq= (const float*)d_in[10]; const float* baq= (const float*)d_in[11];
  const float* wak= (const float*)d_in[12]; const float* bak= (const float*)d_in[13];
  const float* wav= (const float*)d_in[14]; const float* bav= (const float*)d_in[15];
  const float* wo = (const float*)d_in[16]; const float* bo = (const float*)d_in[17];
  const float* wao= (const float*)d_in[18]; const float* bao= (const float*)d_in[19];
  const float* nq = (const float*)d_in[20]; const float* nk = (const float*)d_in[21];
  const float* naq= (const float*)d_in[22]; const float* nak= (const float*)d_in[23];

  const float qsc = (float)(0.08838834764831845 * 1.4426950408889634); // scale * log2(e)

  char* p = (char*)d_ws;
  auto alloc = [&](size_t bytes){ char* r = p; p += bytes; return r; };

  if (ws_size >= (size_t)245366784){
    // ---------- merged path (245.4 MB) ----------
    unsigned short* Xh = (unsigned short*)alloc(12582912);  // [2048][3072] (Xc rows 0..2047)
    unsigned short* Xe = (unsigned short*)alloc(6291456);   // [1024][3072] (Xc rows 2048..3071)
    unsigned short* Wb = (unsigned short*)alloc(113246208); // 6 weight slots bf16
    unsigned short* Yb = (unsigned short*)alloc(56623104);  // [3072][9216]
    unsigned short* Qb = (unsigned short*)alloc(18874368);  // Q [2][24][1536][128]
    unsigned short* Ke = (unsigned short*)alloc(6291456);   // Kenc [2][24][512][128]
    unsigned short* Ki = (unsigned short*)alloc(12582912);  // Kimg [24][2048][128]
    unsigned short* Ve = (unsigned short*)alloc(6291456);   // Vtenc [2][24][128][512]
    unsigned short* Vi = (unsigned short*)alloc(12582912);  // Vtimg [24][128][2048]
    unsigned short* AO = Xh;                                // aliases Xh+Xe (dead by attn)

    k_cast<<<6144,256,0,stream>>>(hs, Xh, 1572864);
    k_cast<<<3072,256,0,stream>>>(ehs, Xe, 786432);
    k_castW<<<55296,256,0,stream>>>(wq, wk, wv, waq, wak, wav, Wb);

    // one merged QKV GEMM over [Xh;Xe]
    k_gemmQKV<<<dim3(24,72),256,0,stream>>>(Xh, Wb, Wb + 28311552, Yb,
                                            bq, bk, bv, baq, bak, bav, 2048);

    unsigned short* Ye = Yb + (long)18874368;               // enc rows (2048*9216)
    k_ppqk<<<12288,256,0,stream>>>(Yb, 9216, 0,    nq,  rc, rs_, Qb, 11, 10, 512, 1536, 0, 512, 1023, qsc);
    k_ppqk<<<12288,256,0,stream>>>(Yb, 9216, 3072, nk,  rc, rs_, Ki, 11, 0,  0,   2048, 1, 512, 1023, 1.0f);
    k_ppv<<<dim3(32,24),256,0,stream>>>(Yb, 9216, 6144, Vi, 2048, 1);
    k_ppqk<<<6144,256,0,stream>>>(Ye, 9216, 0,    naq, rc, rs_, Qb, 10, 9, 0, 1536, 0, 0, 511, qsc);
    k_ppqk<<<6144,256,0,stream>>>(Ye, 9216, 3072, nak, rc, rs_, Ke, 10, 9, 0, 512,  0, 0, 511, 1.0f);
    k_ppv<<<dim3(16,24),256,0,stream>>>(Ye, 9216, 6144, Ve, 512, 0);

    k_attn<<<dim3(24,24,2),256,0,stream>>>(Qb, Ke, Ki, Ve, Vi, AO);

    k_cast<<<9216,256,0,stream>>>(wo,  Wb, 2359296);
    k_cast<<<9216,256,0,stream>>>(wao, Wb + 9437184, 2359296);
    k_gemmO<<<dim3(24,24),256,0,stream>>>(AO, Wb, (float*)d_out, bo, bao);
  } else {
    // ---------- fallback path (170 MB, round-3 structure) ----------
    unsigned short* Xh = (unsigned short*)alloc(12582912);
    unsigned short* Xe = (unsigned short*)alloc(6291456);
    unsigned short* Wb = (unsigned short*)alloc(56623104);  // 3 weight slots
    unsigned short* Yb = (unsigned short*)alloc(37748736);  // [2048][9216]
    unsigned short* Qb = (unsigned short*)alloc(18874368);
    unsigned short* Ke = (unsigned short*)alloc(6291456);
    unsigned short* Ki = (unsigned short*)alloc(12582912);
    unsigned short* Ve = (unsigned short*)alloc(6291456);
    unsigned short* Vi = (unsigned short*)alloc(12582912);
    unsigned short* AO = Xh;

    k_cast<<<6144,256,0,stream>>>(hs, Xh, 1572864);
    k_cast<<<3072,256,0,stream>>>(ehs, Xe, 786432);

    // image fused QKV
    k_cast<<<9216,256,0,stream>>>(wq, Wb, 2359296);
    k_cast<<<9216,256,0,stream>>>(wk, Wb + 9437184, 2359296);
    k_cast<<<9216,256,0,stream>>>(wv, Wb + 18874368, 2359296);
    k_gemmQKV<<<dim3(16,72),256,0,stream>>>(Xh, Wb, Wb, Yb,
                                            bq, bk, bv, bq, bk, bv, 1<<28);
    k_ppqk<<<12288,256,0,stream>>>(Yb, 9216, 0,    nq, rc, rs_, Qb, 11, 10, 512, 1536, 0, 512, 1023, qsc);
    k_ppqk<<<12288,256,0,stream>>>(Yb, 9216, 3072, nk, rc, rs_, Ki, 11, 0,  0,   2048, 1, 512, 1023, 1.0f);
    k_ppv<<<dim3(32,24),256,0,stream>>>(Yb, 9216, 6144, Vi, 2048, 1);

    // encoder fused QKV
    k_cast<<<9216,256,0,stream>>>(waq, Wb, 2359296);
    k_cast<<<9216,256,0,stream>>>(wak, Wb + 9437184, 2359296);
    k_cast<<<9216,256,0,stream>>>(wav, Wb + 18874368, 2359296);
    k_gemmQKV<<<dim3(8,72),256,0,stream>>>(Xe, Wb, Wb, Yb,
                                           baq, bak, bav, baq, bak, bav, 0);
    k_ppqk<<<6144,256,0,stream>>>(Yb, 9216, 0,    naq, rc, rs_, Qb, 10, 9, 0, 1536, 0, 0, 511, qsc);
    k_ppqk<<<6144,256,0,stream>>>(Yb, 9216, 3072, nak, rc, rs_, Ke, 10, 9, 0, 512,  0, 0, 511, 1.0f);
    k_ppv<<<dim3(16,24),256,0,stream>>>(Yb, 9216, 6144, Ve, 512, 0);

    k_attn<<<dim3(24,24,2),256,0,stream>>>(Qb, Ke, Ki, Ve, Vi, AO);

    k_cast<<<9216,256,0,stream>>>(wo,  Wb, 2359296);
    k_cast<<<9216,256,0,stream>>>(wao, Wb + 9437184, 2359296);
    k_gemmO<<<dim3(24,24),256,0,stream>>>(AO, Wb, (float*)d_out, bo, bao);
  }
}

// Round 5
// 729.912 us; speedup vs baseline: 1.0206x; 1.0206x over previous
//
#include <hip/hip_runtime.h>

typedef __attribute__((ext_vector_type(8))) short bf16x8;
typedef __attribute__((ext_vector_type(8))) unsigned short u16x8;
typedef __attribute__((ext_vector_type(4))) unsigned short u16x4;
typedef __attribute__((ext_vector_type(4))) float f32x4;

#define DEV static __device__ __forceinline__

DEV unsigned short f2bf(float f){
  unsigned u = __float_as_uint(f);
  u += 0x7fff + ((u>>16)&1);
  return (unsigned short)(u>>16);
}
DEV float bf2f(unsigned short b){ return __uint_as_float(((unsigned)b)<<16); }

DEV void gll16(const void* g, void* l){
  __builtin_amdgcn_global_load_lds((__attribute__((address_space(1))) unsigned*)(void*)g,
                                   (__attribute__((address_space(3))) unsigned*)l, 16, 0, 0);
}

// ---------------- cast fp32 -> bf16 (vectorized) ----------------
__global__ void k_cast(const float* __restrict__ x, unsigned short* __restrict__ y, int n4){
  int i = blockIdx.x*256 + threadIdx.x;
  if (i >= n4) return;
  f32x4 v = ((const f32x4*)x)[i];
  u16x4 o = { f2bf(v.x), f2bf(v.y), f2bf(v.z), f2bf(v.w) };
  ((u16x4*)y)[i] = o;
}

// ---------------- 6-segment weight cast (one launch for all QKV weights) ----------------
__global__ void k_castW(const float* __restrict__ s0, const float* __restrict__ s1,
                        const float* __restrict__ s2, const float* __restrict__ s3,
                        const float* __restrict__ s4, const float* __restrict__ s5,
                        unsigned short* __restrict__ y){
  unsigned i = blockIdx.x*256 + threadIdx.x;          // < 6*2359296
  unsigned seg = i / 2359296u;                        // uniform per block (9216 blocks/seg)
  unsigned off = i - seg*2359296u;
  const float* s = seg==0?s0: seg==1?s1: seg==2?s2: seg==3?s3: seg==4?s4: s5;
  f32x4 v = ((const f32x4*)s)[off];
  u16x4 o = { f2bf(v.x), f2bf(v.y), f2bf(v.z), f2bf(v.w) };
  ((u16x4*)y)[i] = o;
}

// ---------------- QKV projection GEMM: Y[M][9216] = X @ [Wq|Wk|Wv]^T (+bias) ----------------
// XCD-chunked swizzle: each XCD owns 9 contiguous W-columns (W panel read by 1 XCD only).
__global__ __launch_bounds__(256) void k_gemmP(
    const unsigned short* __restrict__ X, const unsigned short* __restrict__ W,
    unsigned short* __restrict__ Y,
    const float* __restrict__ b0, const float* __restrict__ b1, const float* __restrict__ b2,
    int gxl)   // log2(gridDim.x)
{
  const int K = 3072, N = 9216;
  __shared__ unsigned short As[2][4096];
  __shared__ unsigned short Bs[2][4096];
  const int t = threadIdx.x, w = t>>6, l = t&63;
  int flat = blockIdx.x + (blockIdx.y<<gxl);
  int xc = flat & 7, ii = flat >> 3;
  int by = 9*xc + (ii>>gxl);                 // W column block [0,72)
  int bx = ii & ((1<<gxl)-1);                // X row block
  const int sec = by>=48 ? 2 : (by>=24 ? 1 : 0);      // Q/K/V section
  const int Cl = (by - sec*24)*128;                   // col base within 3072 section
  const int R = bx*128;
  const unsigned short* Wp = W + (long)sec*9437184 + (long)Cl*K;
  const float* bias = (sec==0)?b0:(sec==1)?b1:b2;
  const int wr = w>>1, wc = w&1;
  f32x4 acc[4][4] = {};

  auto stage = [&](int buf, int kt){
    const int k0 = kt*32;
    #pragma unroll
    for (int c=0;c<2;c++){
      int row = c*64 + (t>>2);
      int scol = ((t&3)<<3) ^ ((row&3)<<3);           // 4-way XOR pre-swizzle of source
      gll16(X + (long)(R+row)*K + k0 + scol, &As[buf][c*2048 + w*512]);
      gll16(Wp + (long)row*K + k0 + scol, &Bs[buf][c*2048 + w*512]);
    }
  };

  stage(0,0);
  int buf = 0;
  for (int kt=0; kt<96; kt++){
    __syncthreads();
    if (kt+1 < 96) stage(buf^1, kt+1);
    bf16x8 a[4], b[4];
    #pragma unroll
    for (int m=0;m<4;m++){
      int ar = wr*64 + m*16 + (l&15);
      int ac = ((l>>4)<<3) ^ ((ar&3)<<3);
      a[m] = *(const bf16x8*)&As[buf][ar*32 + ac];
      int br = wc*64 + m*16 + (l&15);
      int bc2 = ((l>>4)<<3) ^ ((br&3)<<3);
      b[m] = *(const bf16x8*)&Bs[buf][br*32 + bc2];
    }
    #pragma unroll
    for (int m=0;m<4;m++)
      #pragma unroll
      for (int n=0;n<4;n++)
        acc[m][n] = __builtin_amdgcn_mfma_f32_16x16x32_bf16(a[m], b[n], acc[m][n], 0,0,0);
    buf ^= 1;
  }

  #pragma unroll
  for (int m=0;m<4;m++){
    int row = R + wr*64 + m*16 + ((l>>4)<<2);
    #pragma unroll
    for (int n=0;n<4;n++){
      int cl = wc*64 + n*16 + (l&15);
      float bvv = bias[Cl + cl];
      long col = (long)by*128 + cl;
      #pragma unroll
      for (int r=0;r<4;r++)
        Y[(long)(row+r)*N + col] = f2bf(acc[m][n][r] + bvv);
    }
  }
}

// ---------------- fused output GEMM (block-diagonal over rows), XCD-chunked swizzle ----------------
__global__ __launch_bounds__(256) void k_gemmO(
    const unsigned short* __restrict__ X, const unsigned short* __restrict__ Wf,
    float* __restrict__ out, const float* __restrict__ bo, const float* __restrict__ bao)
{
  const int K = 3072;
  __shared__ unsigned short As[2][4096];
  __shared__ unsigned short Bs[2][4096];
  const int t = threadIdx.x, w = t>>6, l = t&63;
  int flat = blockIdx.x + 24*blockIdx.y;
  int xc = flat & 7, ii = flat >> 3;         // ii in [0,72)
  int iy = ii/24;
  int by = 3*xc + iy;
  int bx = ii - iy*24;
  const bool enc = bx >= 16;
  const unsigned short* Wp = Wf + (enc ? 9437184 : 0);
  const float* bias = enc ? bao : bo;
  const int R = bx*128, C = by*128;
  long xbase, obase;
  if (!enc){ xbase = (long)(R>>10)*1536 + 512 + (R&1023); obase = (long)R*3072; }
  else { int Rp = R-2048; xbase = (long)(Rp>>9)*1536 + (Rp&511); obase = 6291456 + (long)Rp*3072; }
  const int wr = w>>1, wc = w&1;
  f32x4 acc[4][4] = {};

  auto stage = [&](int buf, int kt){
    const int k0 = kt*32;
    #pragma unroll
    for (int c=0;c<2;c++){
      int row = c*64 + (t>>2);
      int scol = ((t&3)<<3) ^ ((row&3)<<3);
      gll16(X + (xbase+row)*K + k0 + scol, &As[buf][c*2048 + w*512]);
      gll16(Wp + (long)(C+row)*K + k0 + scol, &Bs[buf][c*2048 + w*512]);
    }
  };

  stage(0,0);
  int buf = 0;
  for (int kt=0; kt<96; kt++){
    __syncthreads();
    if (kt+1 < 96) stage(buf^1, kt+1);
    bf16x8 a[4], b[4];
    #pragma unroll
    for (int m=0;m<4;m++){
      int ar = wr*64 + m*16 + (l&15);
      int ac = ((l>>4)<<3) ^ ((ar&3)<<3);
      a[m] = *(const bf16x8*)&As[buf][ar*32 + ac];
      int br = wc*64 + m*16 + (l&15);
      int bc2 = ((l>>4)<<3) ^ ((br&3)<<3);
      b[m] = *(const bf16x8*)&Bs[buf][br*32 + bc2];
    }
    #pragma unroll
    for (int m=0;m<4;m++)
      #pragma unroll
      for (int n=0;n<4;n++)
        acc[m][n] = __builtin_amdgcn_mfma_f32_16x16x32_bf16(a[m], b[n], acc[m][n], 0,0,0);
    buf ^= 1;
  }

  #pragma unroll
  for (int m=0;m<4;m++){
    int rl = wr*64 + m*16 + ((l>>4)<<2);
    #pragma unroll
    for (int n=0;n<4;n++){
      int col = C + wc*64 + n*16 + (l&15);
      float bvv = bias[col];
      #pragma unroll
      for (int r=0;r<4;r++)
        out[obase + (long)(rl+r)*3072 + col] = acc[m][n][r] + bvv;
    }
  }
}

// ---------------- fused RMSNorm + RoPE postprocess (one wave per (token,head)) ----------------
__global__ void k_ppqk(const unsigned short* __restrict__ Y, int ystr, int yoff,
    const float* __restrict__ nw,
    const float* __restrict__ cs, const float* __restrict__ sn, unsigned short* __restrict__ dst,
    int T_log2, int tpb_log2, int dest_off, int S, int no_batch,
    int pos_off, int pos_mask, float qscale)
{
  int rid = blockIdx.x*4 + (threadIdx.x>>6);
  int l = threadIdx.x & 63;
  int h = rid >> T_log2, tk = rid & ((1<<T_log2)-1);
  unsigned pair = *(const unsigned*)(Y + (long)tk*ystr + yoff + h*128 + 2*l);
  float x0 = bf2f((unsigned short)(pair&0xffff));
  float x1 = bf2f((unsigned short)(pair>>16));
  float ss = x0*x0 + x1*x1;
  #pragma unroll
  for (int m=1;m<64;m<<=1) ss += __shfl_xor(ss, m);
  float rr = rsqrtf(ss*(1.0f/128.0f) + 1e-6f);
  x0 *= rr*nw[2*l]; x1 *= rr*nw[2*l+1];
  int p = pos_off + (tk & pos_mask);
  float c0 = cs[p*128 + 2*l], c1 = cs[p*128 + 2*l+1];
  float s0 = sn[p*128 + 2*l], s1 = sn[p*128 + 2*l+1];
  float o0 = (x0*c0 - x1*s0)*qscale;
  float o1 = (x1*c1 + x0*s1)*qscale;
  long idx;
  if (no_batch) idx = (long)h*S + tk;
  else {
    int b = tk >> tpb_log2;
    int sq = dest_off + (tk & ((1<<tpb_log2)-1));
    idx = (long)(b*24+h)*S + sq;
  }
  unsigned out = (unsigned)f2bf(o0) | ((unsigned)f2bf(o1)<<16);
  *(unsigned*)(dst + idx*128 + 2*l) = out;
}

// ---------------- V reorder + transpose: Vt[(b,)h][d][j] ----------------
__global__ void k_ppv(const unsigned short* __restrict__ Y, int ystr, int yoff,
                      unsigned short* __restrict__ Vt, int vstr, int no_batch)
{
  __shared__ unsigned short tileS[64][136];
  int t = threadIdx.x, h = blockIdx.y;
  int tile0 = blockIdx.x*64;
  #pragma unroll
  for (int c=0;c<4;c++){
    int j = c*16 + (t>>4), col = (t&15)*8;
    *(u16x8*)&tileS[j][col] = *(const u16x8*)(Y + (long)(tile0+j)*ystr + yoff + h*128 + col);
  }
  __syncthreads();
  int d = t>>1, half = t&1;
  unsigned short tmp[32];
  #pragma unroll
  for (int i=0;i<32;i++) tmp[i] = tileS[half*32+i][d];
  long base;
  if (no_batch) base = ((long)h*128 + d)*vstr + tile0 + half*32;
  else { int b = tile0>>9; base = ((long)(b*24+h)*128 + d)*vstr + (tile0&511) + half*32; }
  #pragma unroll
  for (int k=0;k<4;k++) *(u16x8*)(Vt + base + k*8) = *(const u16x8*)&tmp[k*8];
}

// ---------------- flash attention: 64 Q-rows/block, KV tiles of 64 ----------------
// Single-buffered K and V, re-scheduled so each stage is covered by a compute
// section: stageV(jt) at tile top (drained at mid barrier, covered by QK+softmax);
// stageK(jt+1) after mid barrier (drained at next top barrier, covered by PV).
__global__ __launch_bounds__(256) void k_attn(
    const unsigned short* __restrict__ Q,
    const unsigned short* __restrict__ Ke, const unsigned short* __restrict__ Ki,
    const unsigned short* __restrict__ Ve, const unsigned short* __restrict__ Vi,
    unsigned short* __restrict__ AO)
{
  __shared__ unsigned short Ks[8192];          // [64 kv][128 d], XOR-swizzled
  __shared__ unsigned short Vs[8192];          // [128 d][64 kv], XOR-swizzled
  __shared__ unsigned short Ps[4][1408];       // per-wave P tile [16][88]
  const int t = threadIdx.x, w = t>>6, l = t&63;
  const int h = blockIdx.y, b = blockIdx.z;
  const int bh = b*24 + h;
  const int q0 = blockIdx.x*64 + w*16;

  auto stageK = [&](int jt){
    const unsigned short* ksrc = (jt < 8) ? Ke + ((long)bh*512 + jt*64)*128
                                          : Ki + ((long)h*2048 + (jt-8)*64)*128;
    #pragma unroll
    for (int c=0;c<4;c++){
      int row = c*16 + (t>>4);
      int col = ((t&15)<<3) ^ ((row&7)<<3);
      gll16(ksrc + row*128 + col, &Ks[c*2048 + w*512]);
    }
  };
  auto stageV = [&](int jt){
    const unsigned short* vsrc; long vstr;
    if (jt < 8){ vsrc = Ve + (long)bh*65536 + jt*64; vstr = 512; }
    else { vsrc = Vi + (long)h*262144 + (jt-8)*64; vstr = 2048; }
    #pragma unroll
    for (int c=0;c<4;c++){
      int row = c*32 + (t>>3);
      int col = ((t&7)<<3) ^ ((row&7)<<3);
      gll16(vsrc + (long)row*vstr + col, &Vs[c*2048 + w*512]);
    }
  };

  bf16x8 qf[4];
  {
    const unsigned short* qp = Q + ((long)bh*1536 + q0 + (l&15))*128 + ((l>>4)<<3);
    #pragma unroll
    for (int kc=0;kc<4;kc++) qf[kc] = *(const bf16x8*)(qp + kc*32);
  }
  f32x4 o[8] = {};
  float mx[4] = {-1e30f,-1e30f,-1e30f,-1e30f};
  float ls[4] = {0,0,0,0};

  stageK(0);
  for (int jt=0; jt<40; jt++){
    __syncthreads();                 // K(jt) landed + visible; all waves past PV(jt-1)
    stageV(jt);                      // covered by QK + softmax below

    f32x4 sf[4];
    __builtin_amdgcn_s_setprio(1);
    #pragma unroll
    for (int ct=0;ct<4;ct++){
      f32x4 s = {};
      #pragma unroll
      for (int kc=0;kc<4;kc++){
        int krow = ct*16 + (l&15);
        int kcol = (kc*32 + ((l>>4)<<3)) ^ ((krow&7)<<3);
        bf16x8 kb = *(const bf16x8*)&Ks[krow*128 + kcol];
        s = __builtin_amdgcn_mfma_f32_16x16x32_bf16(qf[kc], kb, s, 0,0,0);
      }
      sf[ct] = s;
    }
    __builtin_amdgcn_s_setprio(0);

    float pm[4]; int ok = 1;
    #pragma unroll
    for (int r=0;r<4;r++){
      pm[r] = fmaxf(fmaxf(sf[0][r],sf[1][r]), fmaxf(sf[2][r],sf[3][r]));
      ok &= (pm[r] <= mx[r] + 8.0f);
    }
    if (!__all(ok)){
      #pragma unroll
      for (int r=0;r<4;r++){
        float tmax = pm[r];
        #pragma unroll
        for (int m=1;m<16;m<<=1) tmax = fmaxf(tmax, __shfl_xor(tmax, m));
        float mn = fmaxf(mx[r], tmax);
        float al = exp2f(mx[r]-mn);
        mx[r] = mn;
        ls[r] *= al;
        #pragma unroll
        for (int f=0;f<8;f++) o[f][r] *= al;
      }
    }
    #pragma unroll
    for (int ct=0;ct<4;ct++){
      #pragma unroll
      for (int r=0;r<4;r++){
        float pv = exp2f(sf[ct][r]-mx[r]);
        ls[r] += pv;
        int prow = ((l>>4)<<2) + r;
        Ps[w][prow*88 + ct*16 + (l&15)] = f2bf(pv);
      }
    }
    __syncthreads();                 // V(jt) landed; all waves done reading Ks

    if (jt+1 < 40) stageK(jt+1);     // overwrites Ks; covered by PV below

    bf16x8 pa[2];
    #pragma unroll
    for (int kc=0;kc<2;kc++)
      pa[kc] = *(const bf16x8*)&Ps[w][(l&15)*88 + kc*32 + ((l>>4)<<3)];
    __builtin_amdgcn_s_setprio(1);
    #pragma unroll
    for (int f=0;f<8;f++){
      #pragma unroll
      for (int kc=0;kc<2;kc++){
        int vrow = f*16 + (l&15);
        int vcol = (kc*32 + ((l>>4)<<3)) ^ ((vrow&7)<<3);
        bf16x8 vb = *(const bf16x8*)&Vs[vrow*64 + vcol];
        o[f] = __builtin_amdgcn_mfma_f32_16x16x32_bf16(pa[kc], vb, o[f], 0,0,0);
      }
    }
    __builtin_amdgcn_s_setprio(0);
  }

  #pragma unroll
  for (int r=0;r<4;r++){
    #pragma unroll
    for (int m=1;m<16;m<<=1) ls[r] += __shfl_xor(ls[r], m);
  }
  #pragma unroll
  for (int r=0;r<4;r++){
    int qrow = q0 + ((l>>4)<<2) + r;
    float inv = 1.0f/ls[r];
    #pragma unroll
    for (int f=0;f<8;f++){
      AO[((long)b*1536 + qrow)*3072 + h*128 + f*16 + (l&15)] = f2bf(o[f][r]*inv);
    }
  }
}

// ---------------- host launch ----------------
extern "C" void kernel_launch(void* const* d_in, const int* in_sizes, int n_in,
                              void* d_out, int out_size, void* d_ws, size_t ws_size,
                              hipStream_t stream)
{
  const float* hs  = (const float*)d_in[0];
  const float* ehs = (const float*)d_in[1];
  const float* rc  = (const float*)d_in[2];
  const float* rs_ = (const float*)d_in[3];
  const float* wq = (const float*)d_in[4];  const float* bq = (const float*)d_in[5];
  const float* wk = (const float*)d_in[6];  const float* bk = (const float*)d_in[7];
  const float* wv = (const float*)d_in[8];  const float* bv = (const float*)d_in[9];
  const float* waq= (const float*)d_in[10]; const float* baq= (const float*)d_in[11];
  const float* wak= (const float*)d_in[12]; const float* bak= (const float*)d_in[13];
  const float* wav= (const float*)d_in[14]; const float* bav= (const float*)d_in[15];
  const float* wo = (const float*)d_in[16]; const float* bo = (const float*)d_in[17];
  const float* wao= (const float*)d_in[18]; const float* bao= (const float*)d_in[19];
  const float* nq = (const float*)d_in[20]; const float* nk = (const float*)d_in[21];
  const float* naq= (const float*)d_in[22]; const float* nak= (const float*)d_in[23];

  const float qsc = (float)(0.08838834764831845 * 1.4426950408889634); // scale * log2(e)

  char* p = (char*)d_ws;
  auto alloc = [&](size_t bytes){ char* r = p; p += bytes; return r; };

  if (ws_size >= (size_t)245366784){
    // ---------- main path (245.4 MB; confirmed available in round 4) ----------
    unsigned short* Xh = (unsigned short*)alloc(12582912);  // [2048][3072]
    unsigned short* Xe = (unsigned short*)alloc(6291456);   // [1024][3072]
    unsigned short* Wb = (unsigned short*)alloc(113246208); // 6 weight slots bf16
    unsigned short* Yb = (unsigned short*)alloc(56623104);  // [3072][9216]
    unsigned short* Qb = (unsigned short*)alloc(18874368);  // Q [2][24][1536][128]
    unsigned short* Ke = (unsigned short*)alloc(6291456);   // Kenc [2][24][512][128]
    unsigned short* Ki = (unsigned short*)alloc(12582912);  // Kimg [24][2048][128]
    unsigned short* Ve = (unsigned short*)alloc(6291456);   // Vtenc [2][24][128][512]
    unsigned short* Vi = (unsigned short*)alloc(12582912);  // Vtimg [24][128][2048]
    unsigned short* AO = Xh;                                // aliases Xh+Xe (dead by attn)
    unsigned short* Ye = Yb + (long)18874368;               // enc proj rows

    k_cast<<<6144,256,0,stream>>>(hs, Xh, 1572864);
    k_cast<<<3072,256,0,stream>>>(ehs, Xe, 786432);
    k_castW<<<55296,256,0,stream>>>(wq, wk, wv, waq, wak, wav, Wb);

    // split QKV projections (img then enc), XCD-chunked swizzle inside
    k_gemmP<<<dim3(16,72),256,0,stream>>>(Xh, Wb, Yb, bq, bk, bv, 4);
    k_gemmP<<<dim3(8,72),256,0,stream>>>(Xe, Wb + 28311552, Ye, baq, bak, bav, 3);

    k_ppqk<<<12288,256,0,stream>>>(Yb, 9216, 0,    nq,  rc, rs_, Qb, 11, 10, 512, 1536, 0, 512, 1023, qsc);
    k_ppqk<<<12288,256,0,stream>>>(Yb, 9216, 3072, nk,  rc, rs_, Ki, 11, 0,  0,   2048, 1, 512, 1023, 1.0f);
    k_ppv<<<dim3(32,24),256,0,stream>>>(Yb, 9216, 6144, Vi, 2048, 1);
    k_ppqk<<<6144,256,0,stream>>>(Ye, 9216, 0,    naq, rc, rs_, Qb, 10, 9, 0, 1536, 0, 0, 511, qsc);
    k_ppqk<<<6144,256,0,stream>>>(Ye, 9216, 3072, nak, rc, rs_, Ke, 10, 9, 0, 512,  0, 0, 511, 1.0f);
    k_ppv<<<dim3(16,24),256,0,stream>>>(Ye, 9216, 6144, Ve, 512, 0);

    k_attn<<<dim3(24,24,2),256,0,stream>>>(Qb, Ke, Ki, Ve, Vi, AO);

    k_cast<<<9216,256,0,stream>>>(wo,  Wb, 2359296);
    k_cast<<<9216,256,0,stream>>>(wao, Wb + 9437184, 2359296);
    k_gemmO<<<dim3(24,24),256,0,stream>>>(AO, Wb, (float*)d_out, bo, bao);
  } else {
    // ---------- fallback path (169.9 MB): 3-slot weights, enc group reuses Yb rows ----------
    unsigned short* Xh = (unsigned short*)alloc(12582912);
    unsigned short* Xe = (unsigned short*)alloc(6291456);
    unsigned short* Wb = (unsigned short*)alloc(56623104);  // 3 slots
    unsigned short* Yb = (unsigned short*)alloc(37748736);  // [2048][9216]
    unsigned short* Qb = (unsigned short*)alloc(18874368);
    unsigned short* Ke = (unsigned short*)alloc(6291456);
    unsigned short* Ki = (unsigned short*)alloc(12582912);
    unsigned short* Ve = (unsigned short*)alloc(6291456);
    unsigned short* Vi = (unsigned short*)alloc(12582912);
    unsigned short* AO = Xh;

    k_cast<<<6144,256,0,stream>>>(hs, Xh, 1572864);
    k_cast<<<3072,256,0,stream>>>(ehs, Xe, 786432);

    // image QKV
    k_cast<<<9216,256,0,stream>>>(wq, Wb, 2359296);
    k_cast<<<9216,256,0,stream>>>(wk, Wb + 9437184, 2359296);
    k_cast<<<9216,256,0,stream>>>(wv, Wb + 18874368, 2359296);
    k_gemmP<<<dim3(16,72),256,0,stream>>>(Xh, Wb, Yb, bq, bk, bv, 4);
    k_ppqk<<<12288,256,0,stream>>>(Yb, 9216, 0,    nq, rc, rs_, Qb, 11, 10, 512, 1536, 0, 512, 1023, qsc);
    k_ppqk<<<12288,256,0,stream>>>(Yb, 9216, 3072, nk, rc, rs_, Ki, 11, 0,  0,   2048, 1, 512, 1023, 1.0f);
    k_ppv<<<dim3(32,24),256,0,stream>>>(Yb, 9216, 6144, Vi, 2048, 1);

    // encoder QKV (reuses Yb rows 0..1023)
    k_cast<<<9216,256,0,stream>>>(waq, Wb, 2359296);
    k_cast<<<9216,256,0,stream>>>(wak, Wb + 9437184, 2359296);
    k_cast<<<9216,256,0,stream>>>(wav, Wb + 18874368, 2359296);
    k_gemmP<<<dim3(8,72),256,0,stream>>>(Xe, Wb, Yb, baq, bak, bav, 3);
    k_ppqk<<<6144,256,0,stream>>>(Yb, 9216, 0,    naq, rc, rs_, Qb, 10, 9, 0, 1536, 0, 0, 511, qsc);
    k_ppqk<<<6144,256,0,stream>>>(Yb, 9216, 3072, nak, rc, rs_, Ke, 10, 9, 0, 512,  0, 0, 511, 1.0f);
    k_ppv<<<dim3(16,24),256,0,stream>>>(Yb, 9216, 6144, Ve, 512, 0);

    k_attn<<<dim3(24,24,2),256,0,stream>>>(Qb, Ke, Ki, Ve, Vi, AO);

    k_cast<<<9216,256,0,stream>>>(wo,  Wb, 2359296);
    k_cast<<<9216,256,0,stream>>>(wao, Wb + 9437184, 2359296);
    k_gemmO<<<dim3(24,24),256,0,stream>>>(AO, Wb, (float*)d_out, bo, bao);
  }
}

// Round 6
// 709.260 us; speedup vs baseline: 1.0503x; 1.0291x over previous
//
#include <hip/hip_runtime.h>

typedef __attribute__((ext_vector_type(8))) short bf16x8;
typedef __attribute__((ext_vector_type(8))) unsigned short u16x8;
typedef __attribute__((ext_vector_type(4))) unsigned short u16x4;
typedef __attribute__((ext_vector_type(4))) float f32x4;
typedef __attribute__((ext_vector_type(2))) unsigned uint2v;

#define DEV static __device__ __forceinline__

DEV unsigned short f2bf(float f){
  unsigned u = __float_as_uint(f);
  u += 0x7fff + ((u>>16)&1);
  return (unsigned short)(u>>16);
}
DEV float bf2f(unsigned short b){ return __uint_as_float(((unsigned)b)<<16); }
DEV unsigned cvtpk(float lo, float hi){
  unsigned r;
  asm("v_cvt_pk_bf16_f32 %0, %1, %2" : "=v"(r) : "v"(lo), "v"(hi));
  return r;
}

DEV void gll16(const void* g, void* l){
  __builtin_amdgcn_global_load_lds((__attribute__((address_space(1))) unsigned*)(void*)g,
                                   (__attribute__((address_space(3))) unsigned*)l, 16, 0, 0);
}

// ---------------- cast fp32 -> bf16 (vectorized) ----------------
__global__ void k_cast(const float* __restrict__ x, unsigned short* __restrict__ y, int n4){
  int i = blockIdx.x*256 + threadIdx.x;
  if (i >= n4) return;
  f32x4 v = ((const f32x4*)x)[i];
  u16x4 o = { f2bf(v.x), f2bf(v.y), f2bf(v.z), f2bf(v.w) };
  ((u16x4*)y)[i] = o;
}

// ---------------- 6-segment weight cast (one launch for all QKV weights) ----------------
__global__ void k_castW(const float* __restrict__ s0, const float* __restrict__ s1,
                        const float* __restrict__ s2, const float* __restrict__ s3,
                        const float* __restrict__ s4, const float* __restrict__ s5,
                        unsigned short* __restrict__ y){
  unsigned i = blockIdx.x*256 + threadIdx.x;          // < 6*2359296
  unsigned seg = i / 2359296u;                        // uniform per block (9216 blocks/seg)
  unsigned off = i - seg*2359296u;
  const float* s = seg==0?s0: seg==1?s1: seg==2?s2: seg==3?s3: seg==4?s4: s5;
  f32x4 v = ((const f32x4*)s)[off];
  u16x4 o = { f2bf(v.x), f2bf(v.y), f2bf(v.z), f2bf(v.w) };
  ((u16x4*)y)[i] = o;
}

// ---------------- QKV projection GEMM: Y[M][9216] = X @ [Wq|Wk|Wv]^T (+bias) ----------------
__global__ __launch_bounds__(256) void k_gemmP(
    const unsigned short* __restrict__ X, const unsigned short* __restrict__ W,
    unsigned short* __restrict__ Y,
    const float* __restrict__ b0, const float* __restrict__ b1, const float* __restrict__ b2)
{
  const int K = 3072, N = 9216;
  __shared__ unsigned short As[2][4096];
  __shared__ unsigned short Bs[2][4096];
  const int t = threadIdx.x, w = t>>6, l = t&63;
  const int by = blockIdx.y, bx = blockIdx.x;
  const int sec = by>=48 ? 2 : (by>=24 ? 1 : 0);      // Q/K/V section
  const int Cl = (by - sec*24)*128;                   // col base within 3072 section
  const int R = bx*128;
  const unsigned short* Wp = W + (long)sec*9437184 + (long)Cl*K;
  const float* bias = (sec==0)?b0:(sec==1)?b1:b2;
  const int wr = w>>1, wc = w&1;
  f32x4 acc[4][4] = {};

  auto stage = [&](int buf, int kt){
    const int k0 = kt*32;
    #pragma unroll
    for (int c=0;c<2;c++){
      int row = c*64 + (t>>2);
      int scol = ((t&3)<<3) ^ ((row&3)<<3);           // 4-way XOR pre-swizzle of source
      gll16(X + (long)(R+row)*K + k0 + scol, &As[buf][c*2048 + w*512]);
      gll16(Wp + (long)row*K + k0 + scol, &Bs[buf][c*2048 + w*512]);
    }
  };

  stage(0,0);
  int buf = 0;
  for (int kt=0; kt<96; kt++){
    __syncthreads();
    if (kt+1 < 96) stage(buf^1, kt+1);
    bf16x8 a[4], b[4];
    #pragma unroll
    for (int m=0;m<4;m++){
      int ar = wr*64 + m*16 + (l&15);
      int ac = ((l>>4)<<3) ^ ((ar&3)<<3);
      a[m] = *(const bf16x8*)&As[buf][ar*32 + ac];
      int br = wc*64 + m*16 + (l&15);
      int bc2 = ((l>>4)<<3) ^ ((br&3)<<3);
      b[m] = *(const bf16x8*)&Bs[buf][br*32 + bc2];
    }
    #pragma unroll
    for (int m=0;m<4;m++)
      #pragma unroll
      for (int n=0;n<4;n++)
        acc[m][n] = __builtin_amdgcn_mfma_f32_16x16x32_bf16(a[m], b[n], acc[m][n], 0,0,0);
    buf ^= 1;
  }

  #pragma unroll
  for (int m=0;m<4;m++){
    int row = R + wr*64 + m*16 + ((l>>4)<<2);
    #pragma unroll
    for (int n=0;n<4;n++){
      int cl = wc*64 + n*16 + (l&15);
      float bvv = bias[Cl + cl];
      long col = (long)by*128 + cl;
      #pragma unroll
      for (int r=0;r<4;r++)
        Y[(long)(row+r)*N + col] = f2bf(acc[m][n][r] + bvv);
    }
  }
}

// ---------------- fused output GEMM (block-diagonal over rows) ----------------
__global__ __launch_bounds__(256) void k_gemmO(
    const unsigned short* __restrict__ X, const unsigned short* __restrict__ Wf,
    float* __restrict__ out, const float* __restrict__ bo, const float* __restrict__ bao)
{
  const int K = 3072;
  __shared__ unsigned short As[2][4096];
  __shared__ unsigned short Bs[2][4096];
  const int t = threadIdx.x, w = t>>6, l = t&63;
  const int bx = blockIdx.x, by = blockIdx.y;
  const bool enc = bx >= 16;
  const unsigned short* Wp = Wf + (enc ? 9437184 : 0);
  const float* bias = enc ? bao : bo;
  const int R = bx*128, C = by*128;
  long xbase, obase;
  if (!enc){ xbase = (long)(R>>10)*1536 + 512 + (R&1023); obase = (long)R*3072; }
  else { int Rp = R-2048; xbase = (long)(Rp>>9)*1536 + (Rp&511); obase = 6291456 + (long)Rp*3072; }
  const int wr = w>>1, wc = w&1;
  f32x4 acc[4][4] = {};

  auto stage = [&](int buf, int kt){
    const int k0 = kt*32;
    #pragma unroll
    for (int c=0;c<2;c++){
      int row = c*64 + (t>>2);
      int scol = ((t&3)<<3) ^ ((row&3)<<3);
      gll16(X + (xbase+row)*K + k0 + scol, &As[buf][c*2048 + w*512]);
      gll16(Wp + (long)(C+row)*K + k0 + scol, &Bs[buf][c*2048 + w*512]);
    }
  };

  stage(0,0);
  int buf = 0;
  for (int kt=0; kt<96; kt++){
    __syncthreads();
    if (kt+1 < 96) stage(buf^1, kt+1);
    bf16x8 a[4], b[4];
    #pragma unroll
    for (int m=0;m<4;m++){
      int ar = wr*64 + m*16 + (l&15);
      int ac = ((l>>4)<<3) ^ ((ar&3)<<3);
      a[m] = *(const bf16x8*)&As[buf][ar*32 + ac];
      int br = wc*64 + m*16 + (l&15);
      int bc2 = ((l>>4)<<3) ^ ((br&3)<<3);
      b[m] = *(const bf16x8*)&Bs[buf][br*32 + bc2];
    }
    #pragma unroll
    for (int m=0;m<4;m++)
      #pragma unroll
      for (int n=0;n<4;n++)
        acc[m][n] = __builtin_amdgcn_mfma_f32_16x16x32_bf16(a[m], b[n], acc[m][n], 0,0,0);
    buf ^= 1;
  }

  #pragma unroll
  for (int m=0;m<4;m++){
    int rl = wr*64 + m*16 + ((l>>4)<<2);
    #pragma unroll
    for (int n=0;n<4;n++){
      int col = C + wc*64 + n*16 + (l&15);
      float bvv = bias[col];
      #pragma unroll
      for (int r=0;r<4;r++)
        out[obase + (long)(rl+r)*3072 + col] = acc[m][n][r] + bvv;
    }
  }
}

// ---------------- fused RMSNorm + RoPE postprocess (one wave per (token,head)) ----------------
__global__ void k_ppqk(const unsigned short* __restrict__ Y, int ystr, int yoff,
    const float* __restrict__ nw,
    const float* __restrict__ cs, const float* __restrict__ sn, unsigned short* __restrict__ dst,
    int T_log2, int tpb_log2, int dest_off, int S, int no_batch,
    int pos_off, int pos_mask, float qscale)
{
  int rid = blockIdx.x*4 + (threadIdx.x>>6);
  int l = threadIdx.x & 63;
  int h = rid >> T_log2, tk = rid & ((1<<T_log2)-1);
  unsigned pair = *(const unsigned*)(Y + (long)tk*ystr + yoff + h*128 + 2*l);
  float x0 = bf2f((unsigned short)(pair&0xffff));
  float x1 = bf2f((unsigned short)(pair>>16));
  float ss = x0*x0 + x1*x1;
  #pragma unroll
  for (int m=1;m<64;m<<=1) ss += __shfl_xor(ss, m);
  float rr = rsqrtf(ss*(1.0f/128.0f) + 1e-6f);
  x0 *= rr*nw[2*l]; x1 *= rr*nw[2*l+1];
  int p = pos_off + (tk & pos_mask);
  float c0 = cs[p*128 + 2*l], c1 = cs[p*128 + 2*l+1];
  float s0 = sn[p*128 + 2*l], s1 = sn[p*128 + 2*l+1];
  float o0 = (x0*c0 - x1*s0)*qscale;
  float o1 = (x1*c1 + x0*s1)*qscale;
  long idx;
  if (no_batch) idx = (long)h*S + tk;
  else {
    int b = tk >> tpb_log2;
    int sq = dest_off + (tk & ((1<<tpb_log2)-1));
    idx = (long)(b*24+h)*S + sq;
  }
  unsigned out = (unsigned)f2bf(o0) | ((unsigned)f2bf(o1)<<16);
  *(unsigned*)(dst + idx*128 + 2*l) = out;
}

// ---------------- V reorder + transpose: Vt[(b,)h][d][j] ----------------
__global__ void k_ppv(const unsigned short* __restrict__ Y, int ystr, int yoff,
                      unsigned short* __restrict__ Vt, int vstr, int no_batch)
{
  __shared__ unsigned short tileS[64][136];
  int t = threadIdx.x, h = blockIdx.y;
  int tile0 = blockIdx.x*64;
  #pragma unroll
  for (int c=0;c<4;c++){
    int j = c*16 + (t>>4), col = (t&15)*8;
    *(u16x8*)&tileS[j][col] = *(const u16x8*)(Y + (long)(tile0+j)*ystr + yoff + h*128 + col);
  }
  __syncthreads();
  int d = t>>1, half = t&1;
  unsigned short tmp[32];
  #pragma unroll
  for (int i=0;i<32;i++) tmp[i] = tileS[half*32+i][d];
  long base;
  if (no_batch) base = ((long)h*128 + d)*vstr + tile0 + half*32;
  else { int b = tile0>>9; base = ((long)(b*24+h)*128 + d)*vstr + (tile0&511) + half*32; }
  #pragma unroll
  for (int k=0;k<4;k++) *(u16x8*)(Vt + base + k*8) = *(const u16x8*)&tmp[k*8];
}

// ---------------- flash attention: 64 Q-rows/block, KV tiles of 64 ----------------
// SWAPPED QK^T: s = mfma(K_frag, Q_frag) -> lane owns ONE q-row (q = l&15),
// k = ct*16 + (l>>4)*4 + r (consecutive in r) -> P packed via v_cvt_pk_bf16_f32,
// written as 4x ds_write_b64. Scalar per-lane mx/ls; cross-q factors via shfl
// in the (rare) rescale path and epilogue only.
__global__ __launch_bounds__(256) void k_attn(
    const unsigned short* __restrict__ Q,
    const unsigned short* __restrict__ Ke, const unsigned short* __restrict__ Ki,
    const unsigned short* __restrict__ Ve, const unsigned short* __restrict__ Vi,
    unsigned short* __restrict__ AO)
{
  __shared__ unsigned short Ks[8192];          // [64 kv][128 d], XOR-swizzled
  __shared__ unsigned short Vs[8192];          // [128 d][64 kv], XOR-swizzled
  __shared__ unsigned short Ps[4][1408];       // per-wave P tile [16 q][88 k-pad]
  const int t = threadIdx.x, w = t>>6, l = t&63;
  const int h = blockIdx.y, b = blockIdx.z;
  const int bh = b*24 + h;
  const int q0 = blockIdx.x*64 + w*16;
  const int g = l>>4;

  auto stageK = [&](int jt){
    const unsigned short* ksrc = (jt < 8) ? Ke + ((long)bh*512 + jt*64)*128
                                          : Ki + ((long)h*2048 + (jt-8)*64)*128;
    #pragma unroll
    for (int c=0;c<4;c++){
      int row = c*16 + (t>>4);
      int col = ((t&15)<<3) ^ ((row&7)<<3);
      gll16(ksrc + row*128 + col, &Ks[c*2048 + w*512]);
    }
  };
  auto stageV = [&](int jt){
    const unsigned short* vsrc; long vstr;
    if (jt < 8){ vsrc = Ve + (long)bh*65536 + jt*64; vstr = 512; }
    else { vsrc = Vi + (long)h*262144 + (jt-8)*64; vstr = 2048; }
    #pragma unroll
    for (int c=0;c<4;c++){
      int row = c*32 + (t>>3);
      int col = ((t&7)<<3) ^ ((row&7)<<3);
      gll16(vsrc + (long)row*vstr + col, &Vs[c*2048 + w*512]);
    }
  };

  bf16x8 qf[4];
  {
    const unsigned short* qp = Q + ((long)bh*1536 + q0 + (l&15))*128 + (g<<3);
    #pragma unroll
    for (int kc=0;kc<4;kc++) qf[kc] = *(const bf16x8*)(qp + kc*32);
  }
  f32x4 o[8] = {};
  float mx = -1e30f;
  float ls = 0.f;            // per-lane partial sum over own (q, k-slice)

  stageK(0);
  for (int jt=0; jt<40; jt++){
    __syncthreads();                 // K(jt) landed; all waves past PV(jt-1)
    stageV(jt);                      // covered by QK + softmax below

    // S^T tile: sf[ct][r] = S[q = q0 + (l&15)][k = ct*16 + g*4 + r]
    f32x4 sf[4];
    __builtin_amdgcn_s_setprio(1);
    #pragma unroll
    for (int ct=0;ct<4;ct++){
      f32x4 s = {};
      #pragma unroll
      for (int kc=0;kc<4;kc++){
        int krow = ct*16 + (l&15);
        int kcol = (kc*32 + (g<<3)) ^ ((krow&7)<<3);
        bf16x8 kb = *(const bf16x8*)&Ks[krow*128 + kcol];
        s = __builtin_amdgcn_mfma_f32_16x16x32_bf16(kb, qf[kc], s, 0,0,0);  // SWAPPED
      }
      sf[ct] = s;
    }
    __builtin_amdgcn_s_setprio(0);

    // per-lane slice max (own q); defer-max with THR=8 (log2 domain)
    float pm = sf[0][0];
    #pragma unroll
    for (int ct=0;ct<4;ct++)
      #pragma unroll
      for (int r=0;r<4;r++) pm = fmaxf(pm, sf[ct][r]);
    if (!__all(pm <= mx + 8.0f)){
      float tmax = pm;
      tmax = fmaxf(tmax, __shfl_xor(tmax, 16));
      tmax = fmaxf(tmax, __shfl_xor(tmax, 32));     // full-row max for own q
      float mn = fmaxf(mx, tmax);
      float al = exp2f(mx - mn);
      mx = mn;
      ls *= al;
      #pragma unroll
      for (int r=0;r<4;r++){
        float alo = __shfl(al, (l&48) | ((g<<2)+r));  // factor for o-row q' = 4g+r
        #pragma unroll
        for (int f=0;f<8;f++) o[f][r] *= alo;
      }
    }
    // P = exp2(S - mx), pack pairs, write b64; accumulate per-lane ls
    #pragma unroll
    for (int ct=0;ct<4;ct++){
      float p0 = exp2f(sf[ct][0]-mx), p1 = exp2f(sf[ct][1]-mx);
      float p2 = exp2f(sf[ct][2]-mx), p3 = exp2f(sf[ct][3]-mx);
      ls += (p0+p1)+(p2+p3);
      uint2v pk = { cvtpk(p0,p1), cvtpk(p2,p3) };
      *(uint2v*)&Ps[w][(l&15)*88 + ct*16 + (g<<2)] = pk;   // k-pair at natural position
    }
    __syncthreads();                 // V(jt) landed; all waves done reading Ks

    if (jt+1 < 40) stageK(jt+1);     // overwrites Ks; covered by PV below

    bf16x8 pa[2];
    #pragma unroll
    for (int kc=0;kc<2;kc++)
      pa[kc] = *(const bf16x8*)&Ps[w][(l&15)*88 + kc*32 + (g<<3)];
    __builtin_amdgcn_s_setprio(1);
    #pragma unroll
    for (int f=0;f<8;f++){
      #pragma unroll
      for (int kc=0;kc<2;kc++){
        int vrow = f*16 + (l&15);
        int vcol = (kc*32 + (g<<3)) ^ ((vrow&7)<<3);
        bf16x8 vb = *(const bf16x8*)&Vs[vrow*64 + vcol];
        o[f] = __builtin_amdgcn_mfma_f32_16x16x32_bf16(pa[kc], vb, o[f], 0,0,0);
      }
    }
    __builtin_amdgcn_s_setprio(0);
  }

  // finalize: full row-sum for own q, then fetch for o-rows q' = 4g+r
  ls += __shfl_xor(ls, 16);
  ls += __shfl_xor(ls, 32);
  #pragma unroll
  for (int r=0;r<4;r++){
    float lso = __shfl(ls, (l&48) | ((g<<2)+r));
    float inv = 1.0f/lso;
    int qrow = q0 + (g<<2) + r;
    #pragma unroll
    for (int f=0;f<8;f++){
      AO[((long)b*1536 + qrow)*3072 + h*128 + f*16 + (l&15)] = f2bf(o[f][r]*inv);
    }
  }
}

// ---------------- host launch ----------------
extern "C" void kernel_launch(void* const* d_in, const int* in_sizes, int n_in,
                              void* d_out, int out_size, void* d_ws, size_t ws_size,
                              hipStream_t stream)
{
  const float* hs  = (const float*)d_in[0];
  const float* ehs = (const float*)d_in[1];
  const float* rc  = (const float*)d_in[2];
  const float* rs_ = (const float*)d_in[3];
  const float* wq = (const float*)d_in[4];  const float* bq = (const float*)d_in[5];
  const float* wk = (const float*)d_in[6];  const float* bk = (const float*)d_in[7];
  const float* wv = (const float*)d_in[8];  const float* bv = (const float*)d_in[9];
  const float* waq= (const float*)d_in[10]; const float* baq= (const float*)d_in[11];
  const float* wak= (const float*)d_in[12]; const float* bak= (const float*)d_in[13];
  const float* wav= (const float*)d_in[14]; const float* bav= (const float*)d_in[15];
  const float* wo = (const float*)d_in[16]; const float* bo = (const float*)d_in[17];
  const float* wao= (const float*)d_in[18]; const float* bao= (const float*)d_in[19];
  const float* nq = (const float*)d_in[20]; const float* nk = (const float*)d_in[21];
  const float* naq= (const float*)d_in[22]; const float* nak= (const float*)d_in[23];

  const float qsc = (float)(0.08838834764831845 * 1.4426950408889634); // scale * log2(e)

  char* p = (char*)d_ws;
  auto alloc = [&](size_t bytes){ char* r = p; p += bytes; return r; };

  if (ws_size >= (size_t)245366784){
    // ---------- main path (245.4 MB; confirmed available) ----------
    unsigned short* Xh = (unsigned short*)alloc(12582912);  // [2048][3072]
    unsigned short* Xe = (unsigned short*)alloc(6291456);   // [1024][3072]
    unsigned short* Wb = (unsigned short*)alloc(113246208); // 6 weight slots bf16
    unsigned short* Yb = (unsigned short*)alloc(56623104);  // [3072][9216]
    unsigned short* Qb = (unsigned short*)alloc(18874368);  // Q [2][24][1536][128]
    unsigned short* Ke = (unsigned short*)alloc(6291456);   // Kenc [2][24][512][128]
    unsigned short* Ki = (unsigned short*)alloc(12582912);  // Kimg [24][2048][128]
    unsigned short* Ve = (unsigned short*)alloc(6291456);   // Vtenc [2][24][128][512]
    unsigned short* Vi = (unsigned short*)alloc(12582912);  // Vtimg [24][128][2048]
    unsigned short* AO = Xh;                                // aliases Xh+Xe (dead by attn)
    unsigned short* Ye = Yb + (long)18874368;               // enc proj rows

    k_cast<<<6144,256,0,stream>>>(hs, Xh, 1572864);
    k_cast<<<3072,256,0,stream>>>(ehs, Xe, 786432);
    k_castW<<<55296,256,0,stream>>>(wq, wk, wv, waq, wak, wav, Wb);

    k_gemmP<<<dim3(16,72),256,0,stream>>>(Xh, Wb, Yb, bq, bk, bv);
    k_gemmP<<<dim3(8,72),256,0,stream>>>(Xe, Wb + 28311552, Ye, baq, bak, bav);

    k_ppqk<<<12288,256,0,stream>>>(Yb, 9216, 0,    nq,  rc, rs_, Qb, 11, 10, 512, 1536, 0, 512, 1023, qsc);
    k_ppqk<<<12288,256,0,stream>>>(Yb, 9216, 3072, nk,  rc, rs_, Ki, 11, 0,  0,   2048, 1, 512, 1023, 1.0f);
    k_ppv<<<dim3(32,24),256,0,stream>>>(Yb, 9216, 6144, Vi, 2048, 1);
    k_ppqk<<<6144,256,0,stream>>>(Ye, 9216, 0,    naq, rc, rs_, Qb, 10, 9, 0, 1536, 0, 0, 511, qsc);
    k_ppqk<<<6144,256,0,stream>>>(Ye, 9216, 3072, nak, rc, rs_, Ke, 10, 9, 0, 512,  0, 0, 511, 1.0f);
    k_ppv<<<dim3(16,24),256,0,stream>>>(Ye, 9216, 6144, Ve, 512, 0);

    k_attn<<<dim3(24,24,2),256,0,stream>>>(Qb, Ke, Ki, Ve, Vi, AO);

    k_cast<<<9216,256,0,stream>>>(wo,  Wb, 2359296);
    k_cast<<<9216,256,0,stream>>>(wao, Wb + 9437184, 2359296);
    k_gemmO<<<dim3(24,24),256,0,stream>>>(AO, Wb, (float*)d_out, bo, bao);
  } else {
    // ---------- fallback path (169.9 MB): 3-slot weights, enc group reuses Yb rows ----------
    unsigned short* Xh = (unsigned short*)alloc(12582912);
    unsigned short* Xe = (unsigned short*)alloc(6291456);
    unsigned short* Wb = (unsigned short*)alloc(56623104);  // 3 slots
    unsigned short* Yb = (unsigned short*)alloc(37748736);  // [2048][9216]
    unsigned short* Qb = (unsigned short*)alloc(18874368);
    unsigned short* Ke = (unsigned short*)alloc(6291456);
    unsigned short* Ki = (unsigned short*)alloc(12582912);
    unsigned short* Ve = (unsigned short*)alloc(6291456);
    unsigned short* Vi = (unsigned short*)alloc(12582912);
    unsigned short* AO = Xh;

    k_cast<<<6144,256,0,stream>>>(hs, Xh, 1572864);
    k_cast<<<3072,256,0,stream>>>(ehs, Xe, 786432);

    k_cast<<<9216,256,0,stream>>>(wq, Wb, 2359296);
    k_cast<<<9216,256,0,stream>>>(wk, Wb + 9437184, 2359296);
    k_cast<<<9216,256,0,stream>>>(wv, Wb + 18874368, 2359296);
    k_gemmP<<<dim3(16,72),256,0,stream>>>(Xh, Wb, Yb, bq, bk, bv);
    k_ppqk<<<12288,256,0,stream>>>(Yb, 9216, 0,    nq, rc, rs_, Qb, 11, 10, 512, 1536, 0, 512, 1023, qsc);
    k_ppqk<<<12288,256,0,stream>>>(Yb, 9216, 3072, nk, rc, rs_, Ki, 11, 0,  0,   2048, 1, 512, 1023, 1.0f);
    k_ppv<<<dim3(32,24),256,0,stream>>>(Yb, 9216, 6144, Vi, 2048, 1);

    k_cast<<<9216,256,0,stream>>>(waq, Wb, 2359296);
    k_cast<<<9216,256,0,stream>>>(wak, Wb + 9437184, 2359296);
    k_cast<<<9216,256,0,stream>>>(wav, Wb + 18874368, 2359296);
    k_gemmP<<<dim3(8,72),256,0,stream>>>(Xe, Wb, Yb, baq, bak, bav);
    k_ppqk<<<6144,256,0,stream>>>(Yb, 9216, 0,    naq, rc, rs_, Qb, 10, 9, 0, 1536, 0, 0, 511, qsc);
    k_ppqk<<<6144,256,0,stream>>>(Yb, 9216, 3072, nak, rc, rs_, Ke, 10, 9, 0, 512,  0, 0, 511, 1.0f);
    k_ppv<<<dim3(16,24),256,0,stream>>>(Yb, 9216, 6144, Ve, 512, 0);

    k_attn<<<dim3(24,24,2),256,0,stream>>>(Qb, Ke, Ki, Ve, Vi, AO);

    k_cast<<<9216,256,0,stream>>>(wo,  Wb, 2359296);
    k_cast<<<9216,256,0,stream>>>(wao, Wb + 9437184, 2359296);
    k_gemmO<<<dim3(24,24),256,0,stream>>>(AO, Wb, (float*)d_out, bo, bao);
  }
}